// Round 6
// baseline (176.627 us; speedup 1.0000x reference)
//
#include <hip/hip_runtime.h>
#include <cmath>

namespace {

constexpr int N = 32, T = 1024, C = 512, K = 64;
constexpr float EPS = 1e-12f;

typedef short s8v __attribute__((ext_vector_type(8)));   // 8 x bf16 bits
typedef short s4v __attribute__((ext_vector_type(4)));   // 4 x bf16 bits
typedef short s2v __attribute__((ext_vector_type(2)));   // 2 x bf16 bits
typedef float f4v __attribute__((ext_vector_type(4)));   // MFMA accumulator

__device__ inline unsigned short f2bh(float f) {
  __bf16 h = (__bf16)f;
  return __builtin_bit_cast(unsigned short, h);
}
__device__ inline float bh2f(unsigned short u) {
  __bf16 h = __builtin_bit_cast(__bf16, u);
  return (float)h;
}

#define MFMA16(A, B, Cc) __builtin_amdgcn_mfma_f32_16x16x32_bf16((A), (B), (Cc), 0, 0, 0)

// ---------------------------------------------------------------------------
// k_gemm1: logits = x @ W^T + b (split-bf16 3-pass MFMA), softmax over K.
// Double-buffered LDS, one barrier per 64-c chunk. Writes a^T as bf16 HI/LO
// ushort arrays. Also zeroes cnt[n] (consumed by gemm2's last-block norm).
// 256 thr, grid 512.
// ---------------------------------------------------------------------------
__global__ __launch_bounds__(256, 4) void k_gemm1(
    const float* __restrict__ x, const float* __restrict__ W,
    const float* __restrict__ b, unsigned short* __restrict__ aTh,
    unsigned short* __restrict__ aTl, float* __restrict__ asum_part,
    unsigned int* __restrict__ cnt) {
  __shared__ __align__(16) unsigned short sm0[4 * 64 * 72];  // 36864 B
  __shared__ __align__(16) unsigned short sm1[4 * 64 * 72];  // 36864 B
  __shared__ float asum_l[256];

  const int tid = threadIdx.x;
  const int w = tid >> 6, lane = tid & 63, lm = lane & 15, lq = lane >> 4;
  const int th = w >> 1;  // t-half (32 rows)
  const int kh = w & 1;   // k-half (32 cols)
  const long r0 = (long)blockIdx.x * 64;
  const int n = blockIdx.x >> 4, tl = blockIdx.x & 15;

  if (tl == 0 && tid == 0) cnt[n] = 0u;  // re-zero every launch (ws poisoned)

  f4v acc[2][2] = {};
  float4 px0[4], pw0[4], px1[4], pw1[4];

#define G1_LOAD(s, c0)                                                       \
  {                                                                          \
    _Pragma("unroll") for (int r = 0; r < 4; ++r) {                          \
      const int f = tid + r * 256, t = f >> 4, cg = f & 15;                  \
      px##s[r] = *(const float4*)&x[(r0 + t) * C + (c0) + cg * 4];           \
      pw##s[r] = *(const float4*)&W[(long)t * C + (c0) + cg * 4];            \
    }                                                                        \
  }

#define G1_STAGE(buf, s)                                                     \
  {                                                                          \
    unsigned short* xh_s = (buf);                                            \
    unsigned short* xl_s = (buf) + 64 * 72;                                  \
    unsigned short* wh_s = (buf) + 2 * 64 * 72;                              \
    unsigned short* wl_s = (buf) + 3 * 64 * 72;                              \
    _Pragma("unroll") for (int r = 0; r < 4; ++r) {                          \
      const int f = tid + r * 256, t = f >> 4, cg = f & 15;                  \
      const float ex[4] = {px##s[r].x, px##s[r].y, px##s[r].z, px##s[r].w};  \
      const float ew[4] = {pw##s[r].x, pw##s[r].y, pw##s[r].z, pw##s[r].w};  \
      s4v xh, xl, wh, wl;                                                    \
      _Pragma("unroll") for (int i = 0; i < 4; ++i) {                        \
        unsigned short hb = f2bh(ex[i]);                                     \
        xh[i] = (short)hb; xl[i] = (short)f2bh(ex[i] - bh2f(hb));            \
        hb = f2bh(ew[i]);                                                    \
        wh[i] = (short)hb; wl[i] = (short)f2bh(ew[i] - bh2f(hb));            \
      }                                                                      \
      *(s4v*)&xh_s[t * 72 + cg * 4] = xh;                                    \
      *(s4v*)&xl_s[t * 72 + cg * 4] = xl;                                    \
      *(s4v*)&wh_s[t * 72 + cg * 4] = wh;                                    \
      *(s4v*)&wl_s[t * 72 + cg * 4] = wl;                                    \
    }                                                                        \
  }

#define G1_MFMA(buf)                                                         \
  {                                                                          \
    unsigned short* xh_s = (buf);                                            \
    unsigned short* xl_s = (buf) + 64 * 72;                                  \
    unsigned short* wh_s = (buf) + 2 * 64 * 72;                              \
    unsigned short* wl_s = (buf) + 3 * 64 * 72;                              \
    _Pragma("unroll") for (int ks = 0; ks < 2; ++ks) {                       \
      const int col = ks * 32 + lq * 8;                                      \
      s8v ah[2], al[2], bh[2], bl[2];                                        \
      _Pragma("unroll") for (int i = 0; i < 2; ++i) {                        \
        ah[i] = *(const s8v*)&xh_s[(th * 32 + i * 16 + lm) * 72 + col];      \
        al[i] = *(const s8v*)&xl_s[(th * 32 + i * 16 + lm) * 72 + col];      \
        bh[i] = *(const s8v*)&wh_s[(kh * 32 + i * 16 + lm) * 72 + col];      \
        bl[i] = *(const s8v*)&wl_s[(kh * 32 + i * 16 + lm) * 72 + col];      \
      }                                                                      \
      _Pragma("unroll") for (int i = 0; i < 2; ++i)                          \
          _Pragma("unroll") for (int j = 0; j < 2; ++j) {                    \
        acc[i][j] = MFMA16(ah[i], bh[j], acc[i][j]);                         \
        acc[i][j] = MFMA16(ah[i], bl[j], acc[i][j]);                         \
        acc[i][j] = MFMA16(al[i], bh[j], acc[i][j]);                         \
      }                                                                      \
    }                                                                        \
  }

  G1_LOAD(0, 0);
  G1_STAGE(sm0, 0);
  G1_LOAD(1, 64);
  __syncthreads();
  // chunk j lives in reg-set (j&1) and LDS buffer (j&1); one barrier/chunk.
  for (int c0 = 0; c0 < C; c0 += 128) {
    // body A: compute chunk c0 from sm0; stage chunk c0+64 into sm1
    if (c0 + 128 < C) G1_LOAD(0, c0 + 128);
    G1_STAGE(sm1, 1);
    G1_MFMA(sm0);
    __syncthreads();
    // body B: compute chunk c0+64 from sm1; stage chunk c0+128 into sm0
    if (c0 + 192 < C) G1_LOAD(1, c0 + 192);
    if (c0 + 128 < C) G1_STAGE(sm0, 0);
    G1_MFMA(sm1);
    __syncthreads();
  }
#undef G1_LOAD
#undef G1_STAGE
#undef G1_MFMA

  // logits + bias -> Ls[64 t][68] fp32 (in sm0); a^T hi/lo staging in sm1.
  float* Ls = (float*)sm0;                       // 17408 B
  unsigned short* L2h = sm1;                     // [64 k][72 t] 9216 B
  unsigned short* L2l = sm1 + 64 * 72;           // 9216 B
  const float bias[2] = {b[kh * 32 + lm], b[kh * 32 + 16 + lm]};
#pragma unroll
  for (int i = 0; i < 2; ++i)
#pragma unroll
    for (int j = 0; j < 2; ++j)
#pragma unroll
      for (int r = 0; r < 4; ++r)
        Ls[(th * 32 + i * 16 + lq * 4 + r) * 68 + kh * 32 + j * 16 + lm] =
            acc[i][j][r] + bias[j];
  __syncthreads();

  // softmax: 4 threads per t-row, 16 k each, register + shfl
  {
    const int row = tid >> 2, q = tid & 3;
    float av[16];
#pragma unroll
    for (int u = 0; u < 4; ++u)
      *(float4*)&av[u * 4] = *(const float4*)&Ls[row * 68 + q * 16 + u * 4];
    float m = av[0];
#pragma unroll
    for (int i = 1; i < 16; ++i) m = fmaxf(m, av[i]);
    m = fmaxf(m, __shfl_xor(m, 1, 64));
    m = fmaxf(m, __shfl_xor(m, 2, 64));
    float sum = 0.f;
#pragma unroll
    for (int i = 0; i < 16; ++i) {
      av[i] = __expf(av[i] - m);
      sum += av[i];
    }
    sum += __shfl_xor(sum, 1, 64);
    sum += __shfl_xor(sum, 2, 64);
    const float inv = 1.f / sum;
    float ps[16];
#pragma unroll
    for (int i = 0; i < 16; ++i) {
      av[i] *= inv;
      ps[i] = av[i];
      const unsigned short hb = f2bh(av[i]);
      L2h[(q * 16 + i) * 72 + row] = hb;                       // a^T hi
      L2l[(q * 16 + i) * 72 + row] = f2bh(av[i] - bh2f(hb));   // a^T lo
    }
#pragma unroll
    for (int s = 4; s < 64; s <<= 1)
#pragma unroll
      for (int i = 0; i < 16; ++i) ps[i] += __shfl_xor(ps[i], s, 64);
    if (lane < 4) {
#pragma unroll
      for (int i = 0; i < 16; ++i) asum_l[w * 64 + q * 16 + i] = ps[i];
    }
  }
  __syncthreads();

  if (tid < 64) {
    asum_part[(n * 16 + tl) * 64 + tid] = asum_l[tid] + asum_l[64 + tid] +
                                          asum_l[128 + tid] + asum_l[192 + tid];
  }
  {
    const int k = tid >> 2, tg = tid & 3;
    const long gb = ((long)n * K + k) * T + tl * 64 + tg * 16;
    *(s8v*)&aTh[gb] = *(const s8v*)&L2h[k * 72 + tg * 16];
    *(s8v*)&aTh[gb + 8] = *(const s8v*)&L2h[k * 72 + tg * 16 + 8];
    *(s8v*)&aTl[gb] = *(const s8v*)&L2l[k * 72 + tg * 16];
    *(s8v*)&aTl[gb + 8] = *(const s8v*)&L2l[k * 72 + tg * 16 + 8];
  }
}

// ---------------------------------------------------------------------------
// k_gemm2: vlad[n,k,c] = sum_t a[t,k]*x[t,c] - asum*cent, full T per block.
// Double-buffered LDS; a-staging is a pure b128 copy of pre-split aTh/aTl.
// 256 thr, grid N*16 XCD-grouped. Wave = 32k x 16c, acc[2].
// R6: writes UNNORMALIZED values into `out`; last-arriving block per n
// (ticket==15 via device-scope atomic counter) performs k_norm's math in
// place -- removes the 3rd kernel launch + drain. No spinning: the 16th
// arriver simply does the work itself (threadFenceReduction pattern).
// ---------------------------------------------------------------------------
__global__ __launch_bounds__(256, 4) void k_gemm2(
    const float* __restrict__ x, const unsigned short* __restrict__ aTh,
    const unsigned short* __restrict__ aTl,
    const float* __restrict__ asum_part, const float* __restrict__ cent,
    float* __restrict__ out, float* __restrict__ ssq_part,
    unsigned int* __restrict__ cnt) {
  __shared__ __align__(16) unsigned short smA[(2 * 64 + 2 * 32) * 72];  // 27648 B
  __shared__ __align__(16) unsigned short smB[(2 * 64 + 2 * 32) * 72];  // 27648 B
  __shared__ float asum_l[64];
  __shared__ float ssq_l[128];
  __shared__ unsigned int ticket;
  __shared__ float ginv_s;

  const int tid = threadIdx.x;
  const int w = tid >> 6, lane = tid & 63, lm = lane & 15, lq = lane >> 4;
  const int kh = w >> 1;  // 32k half
  const int ch = w & 1;   // 16c half
  // XCD-grouping bijection: all 16 c-chunk blocks of an n on one XCD
  const int p = blockIdx.x;
  const int g = p >> 3;
  const int n = ((g & 3) << 3) | (p & 7);
  const int cq = g >> 2;
  const int c0 = cq * 32;

  if (tid < 64) {
    float s = 0.f;
#pragma unroll
    for (int tl = 0; tl < 16; ++tl) s += asum_part[(n * 16 + tl) * 64 + tid];
    asum_l[tid] = s;
  }

  f4v acc[2] = {};
  const int ak = tid >> 2, atg = tid & 3;  // a-copy mapping: 16+16 ushorts
  s8v pah0[2], pal0[2], pah1[2], pal1[2];
  float4 px0[2], px1[2];

#define G2_LOAD(s, t0)                                                       \
  {                                                                          \
    const long ab = ((long)n * K + ak) * T + (t0) + atg * 16;                \
    pah##s[0] = *(const s8v*)&aTh[ab];                                       \
    pah##s[1] = *(const s8v*)&aTh[ab + 8];                                   \
    pal##s[0] = *(const s8v*)&aTl[ab];                                       \
    pal##s[1] = *(const s8v*)&aTl[ab + 8];                                   \
    const int cg = tid & 7, tq = tid >> 3;                                   \
    _Pragma("unroll") for (int i = 0; i < 2; ++i)                            \
        px##s[i] = *(const float4*)&x[((long)n * T + (t0) + tq * 2 + i) * C +\
                                      c0 + cg * 4];                          \
  }

#define G2_STAGE(buf, s)                                                     \
  {                                                                          \
    unsigned short* ah_s = (buf);                                            \
    unsigned short* al_s = (buf) + 64 * 72;                                  \
    unsigned short* xh_s = (buf) + 2 * 64 * 72;                              \
    unsigned short* xl_s = (buf) + 2 * 64 * 72 + 32 * 72;                    \
    *(s8v*)&ah_s[ak * 72 + atg * 16] = pah##s[0];                            \
    *(s8v*)&ah_s[ak * 72 + atg * 16 + 8] = pah##s[1];                        \
    *(s8v*)&al_s[ak * 72 + atg * 16] = pal##s[0];                            \
    *(s8v*)&al_s[ak * 72 + atg * 16 + 8] = pal##s[1];                        \
    const int cg = tid & 7, tq = tid >> 3;                                   \
    _Pragma("unroll") for (int cc = 0; cc < 4; ++cc) {                       \
      s2v h, l;                                                              \
      _Pragma("unroll") for (int i = 0; i < 2; ++i) {                        \
        const float e = ((const float*)&px##s[i])[cc];                       \
        const unsigned short hb = f2bh(e);                                   \
        h[i] = (short)hb;                                                    \
        l[i] = (short)f2bh(e - bh2f(hb));                                    \
      }                                                                      \
      *(s2v*)&xh_s[(cg * 4 + cc) * 72 + tq * 2] = h;                         \
      *(s2v*)&xl_s[(cg * 4 + cc) * 72 + tq * 2] = l;                         \
    }                                                                        \
  }

#define G2_MFMA(buf)                                                         \
  {                                                                          \
    unsigned short* ah_s = (buf);                                            \
    unsigned short* al_s = (buf) + 64 * 72;                                  \
    unsigned short* xh_s = (buf) + 2 * 64 * 72;                              \
    unsigned short* xl_s = (buf) + 2 * 64 * 72 + 32 * 72;                    \
    _Pragma("unroll") for (int ks = 0; ks < 2; ++ks) {                       \
      const int col = ks * 32 + lq * 8;                                      \
      s8v ah[2], al[2];                                                      \
      _Pragma("unroll") for (int i = 0; i < 2; ++i) {                        \
        ah[i] = *(const s8v*)&ah_s[(kh * 32 + i * 16 + lm) * 72 + col];      \
        al[i] = *(const s8v*)&al_s[(kh * 32 + i * 16 + lm) * 72 + col];      \
      }                                                                      \
      const s8v bh = *(const s8v*)&xh_s[(ch * 16 + lm) * 72 + col];          \
      const s8v bl = *(const s8v*)&xl_s[(ch * 16 + lm) * 72 + col];          \
      _Pragma("unroll") for (int i = 0; i < 2; ++i) {                        \
        acc[i] = MFMA16(ah[i], bh, acc[i]);                                  \
        acc[i] = MFMA16(ah[i], bl, acc[i]);                                  \
        acc[i] = MFMA16(al[i], bh, acc[i]);                                  \
      }                                                                      \
    }                                                                        \
  }

  G2_LOAD(0, 0);
  G2_STAGE(smA, 0);
  G2_LOAD(1, 64);
  __syncthreads();
  for (int t0 = 0; t0 < T; t0 += 128) {
    // body A: compute tile t0 from smA; stage tile t0+64 into smB
    if (t0 + 128 < T) G2_LOAD(0, t0 + 128);
    G2_STAGE(smB, 1);
    G2_MFMA(smA);
    __syncthreads();
    // body B: compute tile t0+64 from smB; stage tile t0+128 into smA
    if (t0 + 192 < T) G2_LOAD(1, t0 + 192);
    if (t0 + 128 < T) G2_STAGE(smA, 0);
    G2_MFMA(smB);
    __syncthreads();
  }
#undef G2_LOAD
#undef G2_STAGE
#undef G2_MFMA

  // fused epilogue: subtract asum*cent, write UNNORMALIZED out, ssq partials
  float ssqp[2][4];
#pragma unroll
  for (int i = 0; i < 2; ++i) {
#pragma unroll
    for (int r = 0; r < 4; ++r) {
      const int k = kh * 32 + i * 16 + lq * 4 + r;
      const float as = asum_l[k];
      const int c = c0 + ch * 16 + lm;
      const float v = acc[i][r] - as * cent[(long)k * C + c];
      out[((long)n * K + k) * C + c] = v;
      ssqp[i][r] = v * v;
    }
  }
#pragma unroll
  for (int i = 0; i < 2; ++i)
#pragma unroll
    for (int r = 0; r < 4; ++r) {
      float s = ssqp[i][r];
      s += __shfl_xor(s, 1, 64);
      s += __shfl_xor(s, 2, 64);
      s += __shfl_xor(s, 4, 64);
      s += __shfl_xor(s, 8, 64);
      ssqp[i][r] = s;
    }
  if (lm == 0) {
#pragma unroll
    for (int i = 0; i < 2; ++i)
#pragma unroll
      for (int r = 0; r < 4; ++r)
        ssq_l[(kh * 32 + i * 16 + lq * 4 + r) * 2 + ch] = ssqp[i][r];
  }
  __syncthreads();
  if (tid < 64)
    ssq_part[(n * 16 + cq) * 64 + tid] = ssq_l[tid * 2] + ssq_l[tid * 2 + 1];

  // ---- last-block-per-n normalization (replaces k_norm) ----
  __threadfence();   // all lanes: make out/ssq_part writes device-visible
  __syncthreads();
  if (tid == 0) ticket = atomicAdd(&cnt[n], 1u);  // device-scope by default
  __syncthreads();
  if (ticket != 15u) return;   // uniform branch: only the 16th arriver stays
  __threadfence();             // acquire side: peers' writes now visible

  float* denom = (float*)smA;      // reuse GEMM LDS
  float* contrib = denom + 64;
  if (tid < 64) {
    float ss = 0.f;
#pragma unroll
    for (int q = 0; q < 16; ++q) ss += ssq_part[(n * 16 + q) * 64 + tid];
    const float d = fmaxf(sqrtf(ss), EPS);
    denom[tid] = d;
    contrib[tid] = ss / (d * d);
  }
  __syncthreads();
  if (tid == 0) {
    float s = 0.f;
#pragma unroll
    for (int k = 0; k < K; ++k) s += contrib[k];
    ginv_s = 1.0f / fmaxf(sqrtf(s), EPS);
  }
  __syncthreads();
  const float ginv = ginv_s;

#pragma unroll
  for (int q = 0; q < 32; ++q) {
    const long off = (long)(tid + q * 256) * 4;
    const int k = (int)(off >> 9);
    float4 v = *(const float4*)&out[(long)n * K * C + off];
    const float sc = ginv / denom[k];
    v.x *= sc; v.y *= sc; v.z *= sc; v.w *= sc;
    *(float4*)&out[(long)n * K * C + off] = v;
  }
}

}  // namespace

extern "C" void kernel_launch(void* const* d_in, const int* in_sizes, int n_in,
                              void* d_out, int out_size, void* d_ws,
                              size_t ws_size, hipStream_t stream) {
  const float* x = reinterpret_cast<const float*>(d_in[0]);     // [N,T,C]
  const float* W = reinterpret_cast<const float*>(d_in[1]);     // [K,C]
  const float* b = reinterpret_cast<const float*>(d_in[2]);     // [K]
  const float* cent = reinterpret_cast<const float*>(d_in[3]);  // [K,C]
  float* out = reinterpret_cast<float*>(d_out);                 // [N, K*C]

  char* pp = reinterpret_cast<char*>(d_ws);
  unsigned short* aTh = reinterpret_cast<unsigned short*>(pp);
  pp += (size_t)N * K * T * sizeof(unsigned short);  // 4 MiB
  unsigned short* aTl = reinterpret_cast<unsigned short*>(pp);
  pp += (size_t)N * K * T * sizeof(unsigned short);  // 4 MiB
  float* asum_part = reinterpret_cast<float*>(pp);
  pp += (size_t)512 * 64 * sizeof(float);            // 128 KiB
  float* ssq_part = reinterpret_cast<float*>(pp);
  pp += (size_t)512 * 64 * sizeof(float);            // 128 KiB
  unsigned int* cnt = reinterpret_cast<unsigned int*>(pp);  // 32 x u32

  k_gemm1<<<(N * T) / 64, 256, 0, stream>>>(x, W, b, aTh, aTl, asum_part, cnt);
  k_gemm2<<<N * 16, 256, 0, stream>>>(x, aTh, aTl, asum_part, cent, out,
                                      ssq_part, cnt);
}

// Round 7
// 130.645 us; speedup vs baseline: 1.3520x; 1.3520x over previous
//
#include <hip/hip_runtime.h>
#include <cmath>

namespace {

constexpr int N = 32, T = 1024, C = 512, K = 64;
constexpr float EPS = 1e-12f;

typedef short s8v __attribute__((ext_vector_type(8)));   // 8 x bf16 bits
typedef short s4v __attribute__((ext_vector_type(4)));   // 4 x bf16 bits
typedef short s2v __attribute__((ext_vector_type(2)));   // 2 x bf16 bits
typedef float f4v __attribute__((ext_vector_type(4)));   // MFMA accumulator

__device__ inline unsigned short f2bh(float f) {
  __bf16 h = (__bf16)f;
  return __builtin_bit_cast(unsigned short, h);
}
__device__ inline float bh2f(unsigned short u) {
  __bf16 h = __builtin_bit_cast(__bf16, u);
  return (float)h;
}

#define MFMA16(A, B, Cc) __builtin_amdgcn_mfma_f32_16x16x32_bf16((A), (B), (Cc), 0, 0, 0)

// ---------------------------------------------------------------------------
// k_gemm1: logits = x @ W^T + b (split-bf16 3-pass MFMA), softmax over K.
// R7: 32-t blocks, grid 1024, SINGLE-buffer LDS 27.6KB -> 4 blocks/CU (was 2).
// R4/R5 showed waves-per-block don't help (lockstep); independent streams
// per CU = blocks/CU. Writes a^T bf16 hi/lo + asum_part[n][32][64].
// ---------------------------------------------------------------------------
__global__ __launch_bounds__(256, 4) void k_gemm1(
    const float* __restrict__ x, const float* __restrict__ W,
    const float* __restrict__ b, unsigned short* __restrict__ aTh,
    unsigned short* __restrict__ aTl, float* __restrict__ asum_part) {
  __shared__ __align__(16) unsigned short sm[13824];  // 27648 B
  __shared__ float asum_l[256];
  unsigned short* xh_s = sm;          // [32 t][72]
  unsigned short* xl_s = sm + 2304;
  unsigned short* wh_s = sm + 4608;   // [64 k][72]
  unsigned short* wl_s = sm + 9216;

  const int tid = threadIdx.x;
  const int w = tid >> 6, lane = tid & 63, lm = lane & 15, lq = lane >> 4;
  const int th = w >> 1;  // t-16-half
  const int kh = w & 1;   // k-32-half
  const int n = blockIdx.x >> 5, tl = blockIdx.x & 31;
  const long r0 = (long)blockIdx.x * 32;

  f4v acc[2] = {};
  float4 px[2], pw[4];

#define G1_LOAD(c0)                                                          \
  {                                                                          \
    const int tq = tid >> 4, cg = tid & 15;                                  \
    _Pragma("unroll") for (int r = 0; r < 2; ++r)                            \
        px[r] = *(const float4*)&x[(r0 + r * 16 + tq) * C + (c0) + cg * 4];  \
    _Pragma("unroll") for (int r = 0; r < 4; ++r)                            \
        pw[r] = *(const float4*)&W[(long)(r * 16 + tq) * C + (c0) + cg * 4]; \
  }

#define G1_STAGE()                                                           \
  {                                                                          \
    const int tq = tid >> 4, cg = tid & 15;                                  \
    _Pragma("unroll") for (int r = 0; r < 2; ++r) {                          \
      const int t = r * 16 + tq;                                             \
      const float e[4] = {px[r].x, px[r].y, px[r].z, px[r].w};               \
      s4v h, l;                                                              \
      _Pragma("unroll") for (int i = 0; i < 4; ++i) {                        \
        unsigned short hb = f2bh(e[i]);                                      \
        h[i] = (short)hb; l[i] = (short)f2bh(e[i] - bh2f(hb));               \
      }                                                                      \
      *(s4v*)&xh_s[t * 72 + cg * 4] = h;                                     \
      *(s4v*)&xl_s[t * 72 + cg * 4] = l;                                     \
    }                                                                        \
    _Pragma("unroll") for (int r = 0; r < 4; ++r) {                          \
      const int k = r * 16 + tq;                                             \
      const float e[4] = {pw[r].x, pw[r].y, pw[r].z, pw[r].w};               \
      s4v h, l;                                                              \
      _Pragma("unroll") for (int i = 0; i < 4; ++i) {                        \
        unsigned short hb = f2bh(e[i]);                                      \
        h[i] = (short)hb; l[i] = (short)f2bh(e[i] - bh2f(hb));               \
      }                                                                      \
      *(s4v*)&wh_s[k * 72 + cg * 4] = h;                                     \
      *(s4v*)&wl_s[k * 72 + cg * 4] = l;                                     \
    }                                                                        \
  }

  G1_LOAD(0);
  for (int c0 = 0; c0 < C; c0 += 64) {
    G1_STAGE();
    __syncthreads();  // staging visible to all waves
    if (c0 + 64 < C) G1_LOAD(c0 + 64);  // flies over the MFMA phase
#pragma unroll
    for (int ks = 0; ks < 2; ++ks) {
      const int col = ks * 32 + lq * 8;
      const s8v ah = *(const s8v*)&xh_s[(th * 16 + lm) * 72 + col];
      const s8v al = *(const s8v*)&xl_s[(th * 16 + lm) * 72 + col];
      s8v bh[2], bl[2];
#pragma unroll
      for (int j = 0; j < 2; ++j) {
        bh[j] = *(const s8v*)&wh_s[(kh * 32 + j * 16 + lm) * 72 + col];
        bl[j] = *(const s8v*)&wl_s[(kh * 32 + j * 16 + lm) * 72 + col];
      }
#pragma unroll
      for (int j = 0; j < 2; ++j) {
        acc[j] = MFMA16(ah, bh[j], acc[j]);
        acc[j] = MFMA16(ah, bl[j], acc[j]);
        acc[j] = MFMA16(al, bh[j], acc[j]);
      }
    }
    __syncthreads();  // buffer consumed; next stage may overwrite
  }
#undef G1_LOAD
#undef G1_STAGE

  // logits + bias -> Ls[32 t][68] fp32 (bytes 0..8704 of sm);
  // a^T hi/lo staging above it (disjoint).
  float* Ls = (float*)sm;                         // 8704 B
  unsigned short* L2h = sm + 4352;                // [64 k][40 t] 5120 B
  unsigned short* L2l = sm + 6912;                // 5120 B
  const float bias[2] = {b[kh * 32 + lm], b[kh * 32 + 16 + lm]};
#pragma unroll
  for (int j = 0; j < 2; ++j)
#pragma unroll
    for (int r = 0; r < 4; ++r)
      Ls[(th * 16 + lq * 4 + r) * 68 + kh * 32 + j * 16 + lm] =
          acc[j][r] + bias[j];
  __syncthreads();

  // softmax: 8 threads per t-row, 8 k each, register + shfl
  {
    const int row = tid >> 3, q = tid & 7;
    float av[8];
#pragma unroll
    for (int u = 0; u < 2; ++u)
      *(float4*)&av[u * 4] = *(const float4*)&Ls[row * 68 + q * 8 + u * 4];
    float m = av[0];
#pragma unroll
    for (int i = 1; i < 8; ++i) m = fmaxf(m, av[i]);
    m = fmaxf(m, __shfl_xor(m, 1, 64));
    m = fmaxf(m, __shfl_xor(m, 2, 64));
    m = fmaxf(m, __shfl_xor(m, 4, 64));
    float sum = 0.f;
#pragma unroll
    for (int i = 0; i < 8; ++i) {
      av[i] = __expf(av[i] - m);
      sum += av[i];
    }
    sum += __shfl_xor(sum, 1, 64);
    sum += __shfl_xor(sum, 2, 64);
    sum += __shfl_xor(sum, 4, 64);
    const float inv = 1.f / sum;
    float ps[8];
#pragma unroll
    for (int i = 0; i < 8; ++i) {
      av[i] *= inv;
      ps[i] = av[i];
      const unsigned short hb = f2bh(av[i]);
      L2h[(q * 8 + i) * 40 + row] = hb;
      L2l[(q * 8 + i) * 40 + row] = f2bh(av[i] - bh2f(hb));
    }
    // sum over the wave's 8 t-rows
#pragma unroll
    for (int s = 8; s < 64; s <<= 1)
#pragma unroll
      for (int i = 0; i < 8; ++i) ps[i] += __shfl_xor(ps[i], s, 64);
    if (lane < 8) {
#pragma unroll
      for (int i = 0; i < 8; ++i) asum_l[w * 64 + q * 8 + i] = ps[i];
    }
  }
  __syncthreads();

  if (tid < 64) {
    asum_part[(n * 32 + tl) * 64 + tid] = asum_l[tid] + asum_l[64 + tid] +
                                          asum_l[128 + tid] + asum_l[192 + tid];
  }
  {
    const int k = tid >> 2, tg = tid & 3;  // 8 t each
    const long gb = ((long)n * K + k) * T + tl * 32 + tg * 8;
    *(s8v*)&aTh[gb] = *(const s8v*)&L2h[k * 40 + tg * 8];
    *(s8v*)&aTl[gb] = *(const s8v*)&L2l[k * 40 + tg * 8];
  }
}

// ---------------------------------------------------------------------------
// k_gemm2: partial vlad over a T-half. Grid N*16*2 = 1024 (XCD-grouped by n),
// single-buffer LDS 27.6KB -> 4 blocks/CU. Each ts-half subtracts its own
// asum_half*cent and writes vpart[ts] (no atomics, no fences -- R6 lesson).
// ---------------------------------------------------------------------------
__global__ __launch_bounds__(256, 4) void k_gemm2(
    const float* __restrict__ x, const unsigned short* __restrict__ aTh,
    const unsigned short* __restrict__ aTl,
    const float* __restrict__ asum_part, const float* __restrict__ cent,
    float* __restrict__ vpart) {
  __shared__ __align__(16) unsigned short sm[13824];  // 27648 B
  __shared__ float asum_l[64];
  unsigned short* ah_s = sm;          // [64 k][72]
  unsigned short* al_s = sm + 4608;
  unsigned short* xh_s = sm + 9216;   // [32 c][72]
  unsigned short* xl_s = sm + 11520;

  const int tid = threadIdx.x;
  const int w = tid >> 6, lane = tid & 63, lm = lane & 15, lq = lane >> 4;
  const int kh = w >> 1;  // 32k half
  const int ch = w & 1;   // 16c half
  // bijection: all blocks of an n on XCD n&7 (round-robin dispatch)
  const int p = blockIdx.x;
  const int g = p >> 3;
  const int n = ((g & 3) << 3) | (p & 7);
  const int h = g >> 2;        // 0..31
  const int cq = h & 15, ts = h >> 4;
  const int c0 = cq * 32;
  const int t_base = ts * 512;
  float* vp = vpart + (size_t)ts * N * K * C;

  if (tid < 64) {
    float s = 0.f;
#pragma unroll
    for (int tl = 0; tl < 16; ++tl)
      s += asum_part[(n * 32 + ts * 16 + tl) * 64 + tid];
    asum_l[tid] = s;
  }

  f4v acc[2] = {};
  const int ak = tid >> 2, atg = tid & 3;
  s8v pah[2], pal[2];
  float4 px[2];

#define G2_LOAD(t0)                                                          \
  {                                                                          \
    const long ab = ((long)n * K + ak) * T + t_base + (t0) + atg * 16;       \
    pah[0] = *(const s8v*)&aTh[ab];                                          \
    pah[1] = *(const s8v*)&aTh[ab + 8];                                      \
    pal[0] = *(const s8v*)&aTl[ab];                                          \
    pal[1] = *(const s8v*)&aTl[ab + 8];                                      \
    const int cg = tid & 7, tq = tid >> 3;                                   \
    _Pragma("unroll") for (int i = 0; i < 2; ++i)                            \
        px[i] = *(const float4*)&x[((long)n * T + t_base + (t0) + tq * 2 +   \
                                    i) * C + c0 + cg * 4];                   \
  }

#define G2_STAGE()                                                           \
  {                                                                          \
    *(s8v*)&ah_s[ak * 72 + atg * 16] = pah[0];                               \
    *(s8v*)&ah_s[ak * 72 + atg * 16 + 8] = pah[1];                           \
    *(s8v*)&al_s[ak * 72 + atg * 16] = pal[0];                               \
    *(s8v*)&al_s[ak * 72 + atg * 16 + 8] = pal[1];                           \
    const int cg = tid & 7, tq = tid >> 3;                                   \
    _Pragma("unroll") for (int cc = 0; cc < 4; ++cc) {                       \
      s2v h, l;                                                              \
      _Pragma("unroll") for (int i = 0; i < 2; ++i) {                        \
        const float e = ((const float*)&px[i])[cc];                          \
        const unsigned short hb = f2bh(e);                                   \
        h[i] = (short)hb;                                                    \
        l[i] = (short)f2bh(e - bh2f(hb));                                    \
      }                                                                      \
      *(s2v*)&xh_s[(cg * 4 + cc) * 72 + tq * 2] = h;                         \
      *(s2v*)&xl_s[(cg * 4 + cc) * 72 + tq * 2] = l;                         \
    }                                                                        \
  }

  G2_LOAD(0);
  for (int t0 = 0; t0 < 512; t0 += 64) {
    G2_STAGE();
    __syncthreads();
    if (t0 + 64 < 512) G2_LOAD(t0 + 64);  // flies over MFMA
#pragma unroll
    for (int ks = 0; ks < 2; ++ks) {
      const int col = ks * 32 + lq * 8;
      s8v ah[2], al[2];
#pragma unroll
      for (int i = 0; i < 2; ++i) {
        ah[i] = *(const s8v*)&ah_s[(kh * 32 + i * 16 + lm) * 72 + col];
        al[i] = *(const s8v*)&al_s[(kh * 32 + i * 16 + lm) * 72 + col];
      }
      const s8v bh = *(const s8v*)&xh_s[(ch * 16 + lm) * 72 + col];
      const s8v bl = *(const s8v*)&xl_s[(ch * 16 + lm) * 72 + col];
#pragma unroll
      for (int i = 0; i < 2; ++i) {
        acc[i] = MFMA16(ah[i], bh, acc[i]);
        acc[i] = MFMA16(ah[i], bl, acc[i]);
        acc[i] = MFMA16(al[i], bh, acc[i]);
      }
    }
    __syncthreads();
  }
#undef G2_LOAD
#undef G2_STAGE

  // epilogue: subtract this half's asum*cent, write partial vlad
#pragma unroll
  for (int i = 0; i < 2; ++i) {
#pragma unroll
    for (int r = 0; r < 4; ++r) {
      const int k = kh * 32 + i * 16 + lq * 4 + r;
      const int c = c0 + ch * 16 + lm;
      const float v = acc[i][r] - asum_l[k] * cent[(long)k * C + c];
      vp[((long)n * K + k) * C + c] = v;
    }
  }
}

// ---------------------------------------------------------------------------
// k_norm: sum the two vlad partials (in registers), intra + global L2 norms,
// write out. Grid N = 32 blocks x 1024 threads (thread: one k, 32 c elems).
// ---------------------------------------------------------------------------
__global__ __launch_bounds__(1024) void k_norm(
    const float* __restrict__ vpart, float* __restrict__ out) {
  __shared__ float denom[64];
  __shared__ float contrib[64];
  __shared__ float ginv_s;

  const int tid = threadIdx.x;
  const int n = blockIdx.x;
  const int k = tid >> 4, q = tid & 15;
  const long base = ((long)n * K + k) * C + q * 4;
  const float* p0 = vpart + base;
  const float* p1 = p0 + (size_t)N * K * C;

  float4 v[8];
#pragma unroll
  for (int j = 0; j < 8; ++j) v[j] = *(const float4*)&p0[j * 64];
#pragma unroll
  for (int j = 0; j < 8; ++j) {
    const float4 bvec = *(const float4*)&p1[j * 64];
    v[j].x += bvec.x; v[j].y += bvec.y; v[j].z += bvec.z; v[j].w += bvec.w;
  }
  float ss = 0.f;
#pragma unroll
  for (int j = 0; j < 8; ++j)
    ss += v[j].x * v[j].x + v[j].y * v[j].y + v[j].z * v[j].z + v[j].w * v[j].w;
  ss += __shfl_xor(ss, 1, 64);
  ss += __shfl_xor(ss, 2, 64);
  ss += __shfl_xor(ss, 4, 64);
  ss += __shfl_xor(ss, 8, 64);
  if (q == 0) {
    const float d = fmaxf(sqrtf(ss), EPS);
    denom[k] = d;
    contrib[k] = ss / (d * d);
  }
  __syncthreads();
  if (tid == 0) {
    float s = 0.f;
#pragma unroll
    for (int kk = 0; kk < K; ++kk) s += contrib[kk];
    ginv_s = 1.0f / fmaxf(sqrtf(s), EPS);
  }
  __syncthreads();
  const float sc = ginv_s / denom[k];
  float* po = out + base;
#pragma unroll
  for (int j = 0; j < 8; ++j) {
    float4 o = v[j];
    o.x *= sc; o.y *= sc; o.z *= sc; o.w *= sc;
    *(float4*)&po[j * 64] = o;
  }
}

}  // namespace

extern "C" void kernel_launch(void* const* d_in, const int* in_sizes, int n_in,
                              void* d_out, int out_size, void* d_ws,
                              size_t ws_size, hipStream_t stream) {
  const float* x = reinterpret_cast<const float*>(d_in[0]);     // [N,T,C]
  const float* W = reinterpret_cast<const float*>(d_in[1]);     // [K,C]
  const float* b = reinterpret_cast<const float*>(d_in[2]);     // [K]
  const float* cent = reinterpret_cast<const float*>(d_in[3]);  // [K,C]
  float* out = reinterpret_cast<float*>(d_out);                 // [N, K*C]

  char* pp = reinterpret_cast<char*>(d_ws);
  unsigned short* aTh = reinterpret_cast<unsigned short*>(pp);
  pp += (size_t)N * K * T * sizeof(unsigned short);  // 4 MiB
  unsigned short* aTl = reinterpret_cast<unsigned short*>(pp);
  pp += (size_t)N * K * T * sizeof(unsigned short);  // 4 MiB
  float* vpart = reinterpret_cast<float*>(pp);
  pp += (size_t)2 * N * K * C * sizeof(float);       // 8 MiB (2 partials)
  float* asum_part = reinterpret_cast<float*>(pp);   // [N][32][64] 256 KiB

  k_gemm1<<<(N * T) / 32, 256, 0, stream>>>(x, W, b, aTh, aTl, asum_part);
  k_gemm2<<<N * 16 * 2, 256, 0, stream>>>(x, aTh, aTl, asum_part, cent, vpart);
  k_norm<<<N, 1024, 0, stream>>>(vpart, out);
}